// Round 10
// baseline (4716.676 us; speedup 1.0000x reference)
//
#include <hip/hip_runtime.h>
#include <hip/hip_bf16.h>
#include <math.h>

typedef __bf16 bf16_t;
typedef __attribute__((ext_vector_type(8))) __bf16 bf16x8;
typedef __attribute__((ext_vector_type(4))) __bf16 bf16x4;
typedef __attribute__((ext_vector_type(4))) float f32x4;

static constexpr int B_ = 16, C_ = 16, T_ = 128, H_ = 8, L_ = 12;
static constexpr int NSEQ = C_ * T_ + 1;      // 2049
static constexpr int M_ = B_ * NSEQ;          // 32784
static constexpr int RB_ = 2052;              // padded rowblocks (513*4)
static constexpr float EPS_ = 1e-5f;

__device__ __forceinline__ float wave_sum(float s) {
    #pragma unroll
    for (int o = 1; o < 64; o <<= 1) s += __shfl_xor(s, o);
    return s;
}

// ============================================================================
// Fragment-packed layout for MFMA 16x16x32 operands:
//   element (row, k) -> [(rb*KB + kb)*512 + lane*8 + e]
//   rb=row/16, kb=k/32, lane=(row%16) + 16*((k%32)/8), e=k%8
// A wave's fragment load for (rb,kb) is one contiguous 1KB read at lane*8.
// ============================================================================

// ---------------- weight conversion to packed layout ----------------
__global__ void conv_pack(const float* __restrict__ W, bf16_t* __restrict__ out,
                          int KB, int NB) {
    size_t i = (size_t)blockIdx.x * 256 + threadIdx.x;
    size_t tot = (size_t)L_ * NB * KB * 512;
    if (i >= tot) return;
    int e = i & 7;
    size_t r = i >> 3;
    int lane = r & 63; r >>= 6;
    int kb = r % KB; r /= KB;
    int nb = r % NB; int l = r / NB;
    int K = KB * 32, N = NB * 16;
    int k = kb * 32 + (lane >> 4) * 8 + e;
    int n = nb * 16 + (lane & 15);
    out[i] = (bf16_t)W[((size_t)l * K + k) * N + n];
}

__global__ void conv_pack_q3(const float* __restrict__ Wq, const float* __restrict__ Wk,
                             const float* __restrict__ Wv, bf16_t* __restrict__ out) {
    size_t i = (size_t)blockIdx.x * 256 + threadIdx.x;
    size_t tot = (size_t)L_ * 48 * 8 * 512;
    if (i >= tot) return;
    int e = i & 7;
    size_t r = i >> 3;
    int lane = r & 63; r >>= 6;
    int kb = r % 8; r /= 8;
    int nb = r % 48; int l = r / 48;
    int k = kb * 32 + (lane >> 4) * 8 + e;
    int n = nb * 16 + (lane & 15);
    const float* src = (n < 256) ? Wq : (n < 512) ? Wk : Wv;
    out[i] = (bf16_t)src[((size_t)l * 256 + k) * 256 + (n & 255)];
}

// ---------------- embedding ----------------
__global__ void embed_kernel(const int* __restrict__ x, const float* __restrict__ emb,
                             const float* __restrict__ ch, const float* __restrict__ cls,
                             float* __restrict__ h) {
    int wave = threadIdx.x >> 6, lane = threadIdx.x & 63;
    int row = blockIdx.x * 4 + wave;
    int d0 = lane * 4;
    float4 o;
    int b = row / NSEQ, n = row % NSEQ;
    if (n == 0) {
        o = *(const float4*)(cls + d0);
    } else {
        int idx = n - 1;
        int c = idx / T_, t = idx % T_;
        int tok = x[(b * C_ + c) * T_ + t];
        float4 ev = *(const float4*)(emb + (size_t)tok * 256 + d0);
        float4 cv = *(const float4*)(ch + c * 256 + d0);
        const float kdiv = -0.03597789207803197f;   // -ln(10000)/256
        float f0 = __expf(d0 * kdiv);
        float f2 = __expf((d0 + 2) * kdiv);
        float a0 = t * f0, a2 = t * f2;
        o.x = ev.x + cv.x + sinf(a0);
        o.y = ev.y + cv.y + cosf(a0);
        o.z = ev.z + cv.z + sinf(a2);
        o.w = ev.w + cv.w + cosf(a2);
    }
    *(float4*)(h + (size_t)row * 256 + d0) = o;
}

// ---------------- layer norm -> packed bf16 (KB=8) ----------------
__global__ void ln_pack(const float* __restrict__ h, const float* __restrict__ g,
                        const float* __restrict__ bb, bf16_t* __restrict__ out) {
    int wave = threadIdx.x >> 6, lane = threadIdx.x & 63;
    int row = blockIdx.x * 4 + wave;
    const float* xp = h + (size_t)row * 256;
    int d0 = lane * 4;
    float4 v = *(const float4*)(xp + d0);
    float s = wave_sum(v.x + v.y + v.z + v.w);
    float mean = s * (1.f / 256.f);
    float4 d;
    d.x = v.x - mean; d.y = v.y - mean; d.z = v.z - mean; d.w = v.w - mean;
    float q = wave_sum(d.x * d.x + d.y * d.y + d.z * d.z + d.w * d.w);
    float rs = rsqrtf(q * (1.f / 256.f) + EPS_);
    float4 gv = *(const float4*)(g + d0);
    float4 bv = *(const float4*)(bb + d0);
    bf16x4 o4;
    o4[0] = (bf16_t)(d.x * rs * gv.x + bv.x);
    o4[1] = (bf16_t)(d.y * rs * gv.y + bv.y);
    o4[2] = (bf16_t)(d.z * rs * gv.z + bv.z);
    o4[3] = (bf16_t)(d.w * rs * gv.w + bv.w);
    // packed address for k0 = lane*4
    int rb = row >> 4, rr = row & 15;
    int kb = lane >> 3, kog = (lane >> 1) & 3, e = (lane & 1) * 4;
    *(bf16x4*)(out + ((size_t)(rb * 8 + kb) * 512) + (rr + 16 * kog) * 8 + e) = o4;
}

// ============================================================================
// Barrier-free, LDS-free GEMM on fragment-packed operands.
// Block = 512 thr = 8 waves; block covers 64 rows x 128 cols.
// Wave w: col-tile nb = bx*8+w (16 cols), 4 rowblocks.  Per 32-K chunk:
// 1 contiguous B-frag load + 4 contiguous A-frag loads (identical across the
// 8 waves -> L1 dedup) + 4 MFMAs.  No LDS, no __syncthreads.
//  EPI 0: Cb[r*N+col] = bf16(acc)           (row-major out, no bias)
//  EPI 1: Cf[r*256+col] += acc + bias       (fp32 residual)
//  EPI 2: packed f1 out = bf16(gelu(acc+bias)), KB_out=32
// ============================================================================
template <int KB, int EPI>
__launch_bounds__(512)
__global__ void gemm_pk(const bf16_t* __restrict__ Apk, const bf16_t* __restrict__ Bpk,
                        const float* __restrict__ bias, float* __restrict__ Cf,
                        bf16_t* __restrict__ Cb, int N) {
    int tid = threadIdx.x, lane = tid & 63, wave = tid >> 6;
    int by = blockIdx.y;
    int nb = blockIdx.x * 8 + wave;
    const bf16_t* bp = Bpk + ((size_t)nb * KB) * 512 + lane * 8;
    const bf16_t* ap = Apk + ((size_t)by * 4 * KB) * 512 + lane * 8;

    f32x4 acc0 = {}, acc1 = {}, acc2 = {}, acc3 = {};
    for (int kc = 0; kc < KB / 8; ++kc) {
        #pragma unroll
        for (int kk = 0; kk < 8; ++kk) {
            int kb = kc * 8 + kk;
            bf16x8 bfv = *(const bf16x8*)(bp + (size_t)kb * 512);
            bf16x8 a0 = *(const bf16x8*)(ap + (size_t)(0 * KB + kb) * 512);
            bf16x8 a1 = *(const bf16x8*)(ap + (size_t)(1 * KB + kb) * 512);
            bf16x8 a2 = *(const bf16x8*)(ap + (size_t)(2 * KB + kb) * 512);
            bf16x8 a3 = *(const bf16x8*)(ap + (size_t)(3 * KB + kb) * 512);
            acc0 = __builtin_amdgcn_mfma_f32_16x16x32_bf16(a0, bfv, acc0, 0, 0, 0);
            acc1 = __builtin_amdgcn_mfma_f32_16x16x32_bf16(a1, bfv, acc1, 0, 0, 0);
            acc2 = __builtin_amdgcn_mfma_f32_16x16x32_bf16(a2, bfv, acc2, 0, 0, 0);
            acc3 = __builtin_amdgcn_mfma_f32_16x16x32_bf16(a3, bfv, acc3, 0, 0, 0);
        }
    }

    int l15 = lane & 15, ksel = lane >> 4;
    int col = nb * 16 + l15;
    int row0 = by * 64;
    float bv = (EPI != 0) ? bias[col] : 0.f;

#define PK_EPILOG(ACC, MF)                                                     \
    {                                                                          \
        _Pragma("unroll")                                                      \
        for (int i = 0; i < 4; ++i) {                                          \
            int r = row0 + (MF) * 16 + ksel * 4 + i;                           \
            if (r < M_) {                                                      \
                float v = ACC[i] + bv;                                         \
                if (EPI == 0) {                                                \
                    Cb[(size_t)r * N + col] = (bf16_t)v;                       \
                } else if (EPI == 1) {                                         \
                    Cf[(size_t)r * 256 + col] += v;                            \
                } else {                                                       \
                    float gl = 0.5f * v * (1.f + erff(v * 0.70710678118654752f)); \
                    int rb = (row0 >> 4) + (MF);                               \
                    int rr = ksel * 4 + i;                                     \
                    Cb[((size_t)(rb * 32 + (col >> 5)) * 512)                  \
                       + (rr + 16 * ((col & 31) >> 3)) * 8 + (col & 7)] = (bf16_t)gl; \
                }                                                              \
            }                                                                  \
        }                                                                      \
    }
    PK_EPILOG(acc0, 0)
    PK_EPILOG(acc1, 1)
    PK_EPILOG(acc2, 2)
    PK_EPILOG(acc3, 3)
#undef PK_EPILOG
}

// ---------------- k column max (over n) ----------------
__global__ void kmax_kernel(const bf16_t* __restrict__ qkv, float* __restrict__ colmax) {
    int bh = blockIdx.x;                 // b*8+h
    int b = bh >> 3, hh = bh & 7;
    int c = threadIdx.x & 31, stripe = threadIdx.x >> 5;
    const bf16_t* base = qkv + (size_t)b * NSEQ * 768 + 256 + hh * 32;
    float m = -1e30f;
    for (int n = stripe; n < NSEQ; n += 8)
        m = fmaxf(m, (float)base[(size_t)n * 768 + c]);
    __shared__ float red[8][32];
    red[stripe][c] = m;
    __syncthreads();
    if (threadIdx.x < 32) {
        float mm = red[0][c];
        #pragma unroll
        for (int s2 = 1; s2 < 8; ++s2) mm = fmaxf(mm, red[s2][c]);
        colmax[bh * 32 + c] = mm;
    }
}

// ---------------- ctx partial: sum_n exp(k-max)*v ; colsum ----------------
__global__ void ctx_kernel(const bf16_t* __restrict__ qkv, const float* __restrict__ colmax,
                           float* __restrict__ ctx_part, float* __restrict__ colsum_part) {
    int blk = blockIdx.x;                // bh*8 + s
    int bh = blk >> 3, s = blk & 7;
    int b = bh >> 3, hh = bh & 7;
    int n0 = s * 257, n1 = min(n0 + 257, NSEQ);
    int d = threadIdx.x & 31, eg = threadIdx.x >> 5;
    float maxd = colmax[bh * 32 + d];
    float acc[4] = {0.f, 0.f, 0.f, 0.f};
    float ksum = 0.f;
    __shared__ float ks[64][32];
    __shared__ float vs[64][32];
    const bf16_t* kbase = qkv + (size_t)b * NSEQ * 768 + 256 + hh * 32;
    const bf16_t* vbase = kbase + 256;
    int lr = threadIdx.x >> 2, lc = (threadIdx.x & 3) * 8;
    for (int c0 = n0; c0 < n1; c0 += 64) {
        int rows = min(64, n1 - c0);
        if (lr < rows) {
            bf16x8 kv8 = *(const bf16x8*)(kbase + (size_t)(c0 + lr) * 768 + lc);
            bf16x8 vv8 = *(const bf16x8*)(vbase + (size_t)(c0 + lr) * 768 + lc);
            #pragma unroll
            for (int j = 0; j < 8; ++j) {
                ks[lr][lc + j] = (float)kv8[j];
                vs[lr][lc + j] = (float)vv8[j];
            }
        }
        __syncthreads();
        for (int r = 0; r < rows; ++r) {
            float ek = __expf(ks[r][d] - maxd);
            if (eg == 0) ksum += ek;
            const float* vr = &vs[r][eg * 4];
            acc[0] += ek * vr[0]; acc[1] += ek * vr[1];
            acc[2] += ek * vr[2]; acc[3] += ek * vr[3];
        }
        __syncthreads();
    }
    float* cp = ctx_part + ((size_t)blk * 32 + d) * 32 + eg * 4;
    cp[0] = acc[0]; cp[1] = acc[1]; cp[2] = acc[2]; cp[3] = acc[3];
    if (eg == 0) colsum_part[blk * 32 + d] = ksum;
}

// ---------------- o = softmax(q)*scale @ ctx -> PACKED att (KB=8) ----------------
__global__ void o_kernel(const bf16_t* __restrict__ qkv, const float* __restrict__ ctx_part,
                         const float* __restrict__ colsum_part, bf16_t* __restrict__ attp) {
    int bh = blockIdx.x, b = bh >> 3, hh = bh & 7;
    int chunk = blockIdx.y;
    __shared__ float ctx[1024];
    __shared__ float csum[32];
    int t = threadIdx.x;
    if (t < 32) {
        float s = 0.f;
        #pragma unroll
        for (int ss = 0; ss < 8; ++ss) s += colsum_part[(bh * 8 + ss) * 32 + t];
        csum[t] = s;
    }
    __syncthreads();
    for (int i = t; i < 1024; i += 256) {
        float s = 0.f;
        #pragma unroll
        for (int ss = 0; ss < 8; ++ss) s += ctx_part[(size_t)(bh * 8 + ss) * 1024 + i];
        ctx[i] = s / csum[i >> 5];
    }
    __syncthreads();
    int e = t & 31, grp = t >> 5;
    int n0 = chunk * 228, n1 = min(n0 + 228, NSEQ);
    for (int n = n0 + grp; n < n1; n += 8) {
        const bf16_t* q = qkv + (size_t)(b * NSEQ + n) * 768 + hh * 32;
        float qv = (float)q[e];
        float mx = qv;
        #pragma unroll
        for (int o2 = 16; o2 > 0; o2 >>= 1) mx = fmaxf(mx, __shfl_xor(mx, o2, 32));
        float ev = __expf(qv - mx);
        float sm = ev;
        #pragma unroll
        for (int o2 = 16; o2 > 0; o2 >>= 1) sm += __shfl_xor(sm, o2, 32);
        float p = ev * 0.17677669529663689f / sm;   // dh^-0.5 / sum
        float s = 0.f;
        #pragma unroll
        for (int dd = 0; dd < 32; ++dd) s += __shfl(p, dd, 32) * ctx[dd * 32 + e];
        int row = b * NSEQ + n;
        attp[((size_t)((row >> 4) * 8 + hh) * 512) + ((row & 15) + 16 * (e >> 3)) * 8 + (e & 7)]
            = (bf16_t)s;
    }
}

// ---------------- classifier head: one wave per (b, cls) ----------------
__global__ void head_kernel(const float* __restrict__ h, const float* __restrict__ Wh,
                            const float* __restrict__ bh, float* __restrict__ out) {
    int idx = blockIdx.x;                 // 0..79 = b*5 + c
    int b = idx / 5, c = idx % 5;
    int lane = threadIdx.x;
    const float* xp = h + (size_t)b * NSEQ * 256;
    float s = 0.f;
    #pragma unroll
    for (int d0 = 0; d0 < 256; d0 += 64) s += xp[d0 + lane] * Wh[(d0 + lane) * 5 + c];
    s = wave_sum(s);
    if (lane == 0) out[idx] = s + bh[c];
}

extern "C" void kernel_launch(void* const* d_in, const int* in_sizes, int n_in,
                              void* d_out, int out_size, void* d_ws, size_t ws_size,
                              hipStream_t stream) {
    const int*   x    = (const int*)d_in[0];
    const float* emb  = (const float*)d_in[1];
    const float* ch   = (const float*)d_in[2];
    const float* cls  = (const float*)d_in[3];
    const float* Wq   = (const float*)d_in[4];
    const float* Wk   = (const float*)d_in[5];
    const float* Wv   = (const float*)d_in[6];
    const float* Wo   = (const float*)d_in[7];
    const float* bo   = (const float*)d_in[8];
    const float* g1   = (const float*)d_in[9];
    const float* b1   = (const float*)d_in[10];
    const float* W1   = (const float*)d_in[11];
    const float* bf1  = (const float*)d_in[12];
    const float* W2   = (const float*)d_in[13];
    const float* bf2  = (const float*)d_in[14];
    const float* g2   = (const float*)d_in[15];
    const float* b2   = (const float*)d_in[16];
    const float* Wh   = (const float*)d_in[17];
    const float* bh   = (const float*)d_in[18];

    char* ws = (char*)d_ws;
    size_t off = 0;
    float*  h      = (float*)(ws + off);  off += (size_t)M_ * 256 * 4;            // 33,570,816
    bf16_t* qkv    = (bf16_t*)(ws + off); off += (size_t)M_ * 768 * 2;            // 50,356,224
    bf16_t* yn_pk  = (bf16_t*)(ws + off); off += (size_t)RB_ * 8 * 512 * 2;       // 16,809,984
    bf16_t* att_pk = (bf16_t*)(ws + off); off += (size_t)RB_ * 8 * 512 * 2;       // 16,809,984
    bf16_t* f1_pk  = (bf16_t*)(ws + off); off += (size_t)RB_ * 32 * 512 * 2;      // 67,239,936
    float*  ctxp   = (float*)(ws + off);  off += (size_t)16 * 8 * 8 * 1024 * 4;   // 4,194,304
    float*  csump  = (float*)(ws + off);  off += (size_t)16 * 8 * 8 * 32 * 4;     // 131,072
    float*  cmax   = (float*)(ws + off);  off += (size_t)16 * 8 * 32 * 4;         // 16,384
    bf16_t* wqkv_p = (bf16_t*)(ws + off); off += (size_t)L_ * 768 * 256 * 2;      // 4,718,592
    bf16_t* wo_p   = (bf16_t*)(ws + off); off += (size_t)L_ * 256 * 256 * 2;      // 1,572,864
    bf16_t* w1_p   = (bf16_t*)(ws + off); off += (size_t)L_ * 1024 * 256 * 2;     // 6,291,456
    bf16_t* w2_p   = (bf16_t*)(ws + off); off += (size_t)L_ * 256 * 1024 * 2;     // 6,291,456
    (void)ws_size; (void)in_sizes; (void)n_in; (void)out_size;

    conv_pack_q3<<<9216, 256, 0, stream>>>(Wq, Wk, Wv, wqkv_p);
    conv_pack<<<3072, 256, 0, stream>>>(Wo, wo_p, 8, 16);
    conv_pack<<<12288, 256, 0, stream>>>(W1, w1_p, 8, 64);
    conv_pack<<<12288, 256, 0, stream>>>(W2, w2_p, 32, 16);

    embed_kernel<<<M_ / 4, 256, 0, stream>>>(x, emb, ch, cls, h);

    for (int l = 0; l < L_; ++l) {
        // LN1 -> packed yn
        ln_pack<<<M_ / 4, 256, 0, stream>>>(h, g1 + l * 256, b1 + l * 256, yn_pk);
        // QKV -> qkv row-major [M][768]
        gemm_pk<8, 0><<<dim3(6, 513), 512, 0, stream>>>(
            yn_pk, wqkv_p + (size_t)l * 768 * 256, nullptr, nullptr, qkv, 768);
        kmax_kernel<<<128, 256, 0, stream>>>(qkv, cmax);
        ctx_kernel<<<1024, 256, 0, stream>>>(qkv, cmax, ctxp, csump);
        o_kernel<<<dim3(128, 9), 256, 0, stream>>>(qkv, ctxp, csump, att_pk);
        // Wo + bias + residual into h
        gemm_pk<8, 1><<<dim3(2, 513), 512, 0, stream>>>(
            att_pk, wo_p + (size_t)l * 256 * 256, bo + l * 256, h, nullptr, 256);
        // LN2 -> packed yn
        ln_pack<<<M_ / 4, 256, 0, stream>>>(h, g2 + l * 256, b2 + l * 256, yn_pk);
        // FF1 + GELU -> packed f1
        gemm_pk<8, 2><<<dim3(8, 513), 512, 0, stream>>>(
            yn_pk, w1_p + (size_t)l * 1024 * 256, bf1 + l * 1024, nullptr, f1_pk, 1024);
        // FF2 + bias + residual into h
        gemm_pk<32, 1><<<dim3(2, 513), 512, 0, stream>>>(
            f1_pk, w2_p + (size_t)l * 256 * 1024, bf2 + l * 256, h, nullptr, 256);
    }

    head_kernel<<<80, 64, 0, stream>>>(h, Wh, bh, (float*)d_out);
}

// Round 11
// 3556.597 us; speedup vs baseline: 1.3262x; 1.3262x over previous
//
#include <hip/hip_runtime.h>
#include <hip/hip_bf16.h>
#include <math.h>

typedef __bf16 bf16_t;
typedef __attribute__((ext_vector_type(8))) __bf16 bf16x8;
typedef __attribute__((ext_vector_type(4))) __bf16 bf16x4;
typedef __attribute__((ext_vector_type(4))) float f32x4;

static constexpr int B_ = 16, C_ = 16, T_ = 128, H_ = 8, L_ = 12;
static constexpr int NSEQ = C_ * T_ + 1;      // 2049
static constexpr int M_ = B_ * NSEQ;          // 32784
static constexpr int MPAD = 32896;            // 257*128
static constexpr float EPS_ = 1e-5f;

__device__ __forceinline__ float wave_sum(float s) {
    #pragma unroll
    for (int o = 1; o < 64; o <<= 1) s += __shfl_xor(s, o);
    return s;
}

// fast exact-grade erf-based GELU (A&S 7.1.26, |eps|<1.5e-7)
__device__ __forceinline__ float gelu_f(float v) {
    float ax = fabsf(v) * 0.70710678118654752f;
    float t = 1.f / (1.f + 0.3275911f * ax);
    float p = t * (0.254829592f + t * (-0.284496736f + t * (1.421413741f +
              t * (-1.453152027f + t * 1.061405429f))));
    float erf_abs = 1.f - p * __expf(-ax * ax);
    float erf = (v < 0.f) ? -erf_abs : erf_abs;
    return 0.5f * v * (1.f + erf);
}

// ---------------- weight conversion to W' layout [L][K/8][N][8] ----------------
__global__ void conv_w(const float* __restrict__ W, bf16_t* __restrict__ out, int K, int N) {
    size_t i = (size_t)blockIdx.x * 256 + threadIdx.x;
    size_t per = (size_t)K * N;
    size_t tot = (size_t)L_ * per;
    if (i >= tot) return;
    int kl = i & 7;
    size_t r = i >> 3;
    int n = r % N;
    size_t r2 = r / N;
    int kh = r2 % (K >> 3);
    int l = r2 / (K >> 3);
    out[i] = (bf16_t)W[(size_t)l * per + (size_t)(kh * 8 + kl) * N + n];
}

__global__ void conv_wq3(const float* __restrict__ Wq, const float* __restrict__ Wk,
                         const float* __restrict__ Wv, bf16_t* __restrict__ out) {
    size_t i = (size_t)blockIdx.x * 256 + threadIdx.x;
    size_t tot = (size_t)L_ * 32 * 768 * 8;
    if (i >= tot) return;
    int kl = i & 7;
    size_t r = i >> 3;
    int n = r % 768;
    size_t r2 = r / 768;
    int kh = r2 % 32;
    int l = r2 / 32;
    const float* src = (n < 256) ? Wq : (n < 512) ? Wk : Wv;
    out[i] = (bf16_t)src[(size_t)l * 65536 + (size_t)(kh * 8 + kl) * 256 + (n & 255)];
}

// ---------------- embedding ----------------
__global__ void embed_kernel(const int* __restrict__ x, const float* __restrict__ emb,
                             const float* __restrict__ ch, const float* __restrict__ cls,
                             float* __restrict__ h) {
    int wave = threadIdx.x >> 6, lane = threadIdx.x & 63;
    int row = blockIdx.x * 4 + wave;
    int d0 = lane * 4;
    float4 o;
    int b = row / NSEQ, n = row % NSEQ;
    if (n == 0) {
        o = *(const float4*)(cls + d0);
    } else {
        int idx = n - 1;
        int c = idx / T_, t = idx % T_;
        int tok = x[(b * C_ + c) * T_ + t];
        float4 ev = *(const float4*)(emb + (size_t)tok * 256 + d0);
        float4 cv = *(const float4*)(ch + c * 256 + d0);
        const float kdiv = -0.03597789207803197f;   // -ln(10000)/256
        float f0 = __expf(d0 * kdiv);
        float f2 = __expf((d0 + 2) * kdiv);
        float a0 = t * f0, a2 = t * f2;
        o.x = ev.x + cv.x + sinf(a0);
        o.y = ev.y + cv.y + cosf(a0);
        o.z = ev.z + cv.z + sinf(a2);
        o.w = ev.w + cv.w + cosf(a2);
    }
    *(float4*)(h + (size_t)row * 256 + d0) = o;
}

// ============================================================================
// A-resident barrier-free GEMM with SWAPPED-OPERAND MFMA (coalesced epilogue).
// Block = 128-row stripe (8 waves, 512 thr).  A (optionally layer-normed)
// staged ONCE into 64KB swizzled LDS; ONE barrier; then NT col-tiles with
// weights streamed L2->reg from W' [K/8][N][8].
// mfma(b,a,acc): lane(l15,ksel) reg i holds C[row0+m*16+l15][tile+ksel*4+i]
// -> epilogue = contiguous 8B/16B stores per fragment.
// SRC 0: A = layer_norm(h fp32)      SRC 1: A = bf16 [MPAD][256]
// EPI 0: Cb=bf16(acc)  EPI 1: Cf += acc+bias  EPI 2: Cb=bf16(gelu(acc+bias))
// ============================================================================
template <int SRC, int EPI, int NT>
__launch_bounds__(512)
__global__ void gemm_ar(const void* __restrict__ Asrc, const float* __restrict__ lng,
                        const float* __restrict__ lnb, const bf16_t* __restrict__ Wp,
                        const float* __restrict__ bias, float* __restrict__ Cf,
                        bf16_t* __restrict__ Cb, int N) {
    __shared__ bf16_t yn[128 * 256];
    int tid = threadIdx.x;
    int row0 = blockIdx.y * 128;
    int row = tid >> 2, q4 = tid & 3;
    int sx = row & 7;

    if (SRC == 0) {
        const float* rp = (const float*)Asrc + (size_t)(row0 + row) * 256;
        bool ok = (row0 + row) < M_;
        float v[64];
        float sum = 0.f, sq = 0.f;
        #pragma unroll
        for (int j = 0; j < 16; ++j) {
            float4 t = ok ? *(const float4*)(rp + (q4 + j * 4) * 4)
                          : float4{0.f, 0.f, 0.f, 0.f};
            v[j*4+0] = t.x; v[j*4+1] = t.y; v[j*4+2] = t.z; v[j*4+3] = t.w;
            sum += t.x + t.y + t.z + t.w;
            sq  += t.x*t.x + t.y*t.y + t.z*t.z + t.w*t.w;
        }
        sum += __shfl_xor(sum, 1); sum += __shfl_xor(sum, 2);
        sq  += __shfl_xor(sq, 1);  sq  += __shfl_xor(sq, 2);
        float mean = sum * (1.f/256.f);
        float var  = sq * (1.f/256.f) - mean*mean;
        float rs = rsqrtf(var + EPS_);
        #pragma unroll
        for (int j = 0; j < 16; ++j) {
            int ce = q4 + j * 4;
            int colb = ce * 4;
            float4 gv = *(const float4*)(lng + colb);
            float4 bv = *(const float4*)(lnb + colb);
            bf16x4 o4;
            o4[0] = (bf16_t)((v[j*4+0]-mean)*rs*gv.x + bv.x);
            o4[1] = (bf16_t)((v[j*4+1]-mean)*rs*gv.y + bv.y);
            o4[2] = (bf16_t)((v[j*4+2]-mean)*rs*gv.z + bv.z);
            o4[3] = (bf16_t)((v[j*4+3]-mean)*rs*gv.w + bv.w);
            int cg = ce >> 1, hf = ce & 1;
            *(bf16x4*)(&yn[row*256 + ((cg ^ sx) << 3) + hf*4]) = o4;
        }
    } else {
        const bf16_t* rp = (const bf16_t*)Asrc + (size_t)(row0 + row) * 256;
        #pragma unroll
        for (int j = 0; j < 8; ++j) {
            int cg = q4 * 8 + j;
            bf16x8 t = *(const bf16x8*)(rp + cg * 8);
            *(bf16x8*)(&yn[row*256 + ((cg ^ sx) << 3)]) = t;
        }
    }
    __syncthreads();

    int lane = tid & 63, wave = tid >> 6;
    int l15 = lane & 15, ksel = lane >> 4;
    #pragma unroll
    for (int t = 0; t < NT; ++t) {
        int tbase = (blockIdx.x * NT + t) * 128 + wave * 16;
        int col = tbase + l15;                 // B-frag lane col
        const bf16_t* bp = Wp + ((size_t)ksel * N + col) * 8;
        f32x4 acc[8] = {};
        #pragma unroll
        for (int kk = 0; kk < 8; ++kk) {
            bf16x8 bf = *(const bf16x8*)(bp + (size_t)kk * 32 * N);
            #pragma unroll
            for (int m = 0; m < 8; ++m) {
                int r = m * 16 + l15;
                bf16x8 af = *(const bf16x8*)(&yn[r*256 + (((kk*4+ksel) ^ (r&7)) << 3)]);
                acc[m] = __builtin_amdgcn_mfma_f32_16x16x32_bf16(bf, af, acc[m], 0, 0, 0);
            }
        }
        int colb = tbase + ksel * 4;           // epilogue: 4 consecutive cols
        #pragma unroll
        for (int m = 0; m < 8; ++m) {
            int r = row0 + m * 16 + l15;
            if (r < M_) {
                if (EPI == 0) {
                    bf16x4 o4;
                    #pragma unroll
                    for (int i = 0; i < 4; ++i) o4[i] = (bf16_t)acc[m][i];
                    *(bf16x4*)(Cb + (size_t)r * N + colb) = o4;
                } else if (EPI == 1) {
                    float4 bv = *(const float4*)(bias + colb);
                    float4* hp = (float4*)(Cf + (size_t)r * 256 + colb);
                    float4 hv = *hp;
                    hv.x += acc[m][0] + bv.x; hv.y += acc[m][1] + bv.y;
                    hv.z += acc[m][2] + bv.z; hv.w += acc[m][3] + bv.w;
                    *hp = hv;
                } else {
                    float4 bv = *(const float4*)(bias + colb);
                    bf16x4 o4;
                    o4[0] = (bf16_t)gelu_f(acc[m][0] + bv.x);
                    o4[1] = (bf16_t)gelu_f(acc[m][1] + bv.y);
                    o4[2] = (bf16_t)gelu_f(acc[m][2] + bv.z);
                    o4[3] = (bf16_t)gelu_f(acc[m][3] + bv.w);
                    *(bf16x4*)(Cb + (size_t)r * N + colb) = o4;
                }
            }
        }
    }
}

// ============================================================================
// FF2 chunked, swapped-operand: h += f1[MPAD][1024] @ W2' + bias.
// Output tile 128x128; 4 K-chunks of 256 staged through 64KB swizzled LDS.
// ============================================================================
__launch_bounds__(512)
__global__ void gemm_ff2c(const bf16_t* __restrict__ f1, const bf16_t* __restrict__ W2p,
                          const float* __restrict__ bias, float* __restrict__ hio) {
    __shared__ bf16_t as[128 * 256];
    int tid = threadIdx.x;
    int row0 = blockIdx.y * 128;
    int lane = tid & 63, wave = tid >> 6;
    int l15 = lane & 15, ksel = lane >> 4;
    int col = blockIdx.x * 128 + wave * 16 + l15;
    int row = tid >> 2, q4 = tid & 3;
    int sx = row & 7;
    const bf16_t* rp = f1 + (size_t)(row0 + row) * 1024;
    f32x4 acc[8] = {};

    for (int c = 0; c < 4; ++c) {
        if (c) __syncthreads();
        #pragma unroll
        for (int j = 0; j < 8; ++j) {
            int cg = q4 * 8 + j;
            bf16x8 t = *(const bf16x8*)(rp + c * 256 + cg * 8);
            *(bf16x8*)(&as[row*256 + ((cg ^ sx) << 3)]) = t;
        }
        __syncthreads();
        const bf16_t* bp = W2p + ((size_t)(c * 32 + ksel) * 256 + col) * 8;
        #pragma unroll
        for (int kk = 0; kk < 8; ++kk) {
            bf16x8 bf = *(const bf16x8*)(bp + (size_t)kk * 32 * 256);
            #pragma unroll
            for (int m = 0; m < 8; ++m) {
                int r = m * 16 + l15;
                bf16x8 af = *(const bf16x8*)(&as[r*256 + (((kk*4+ksel) ^ (r&7)) << 3)]);
                acc[m] = __builtin_amdgcn_mfma_f32_16x16x32_bf16(bf, af, acc[m], 0, 0, 0);
            }
        }
    }

    int colb = blockIdx.x * 128 + wave * 16 + ksel * 4;
    float4 bv = *(const float4*)(bias + colb);
    #pragma unroll
    for (int m = 0; m < 8; ++m) {
        int r = row0 + m * 16 + l15;
        if (r < M_) {
            float4* hp = (float4*)(hio + (size_t)r * 256 + colb);
            float4 hv = *hp;
            hv.x += acc[m][0] + bv.x; hv.y += acc[m][1] + bv.y;
            hv.z += acc[m][2] + bv.z; hv.w += acc[m][3] + bv.w;
            *hp = hv;
        }
    }
}

// ---------------- ctx partial: sum_n exp(k)*v ; colsum (no max: |k| bounded) ----------------
__global__ void ctx_kernel(const bf16_t* __restrict__ qkv,
                           float* __restrict__ ctx_part, float* __restrict__ colsum_part) {
    int blk = blockIdx.x;                // bh*8 + s
    int bh = blk >> 3, s = blk & 7;
    int b = bh >> 3, hh = bh & 7;
    int n0 = s * 257, n1 = min(n0 + 257, NSEQ);
    int d = threadIdx.x & 31, eg = threadIdx.x >> 5;
    float acc[4] = {0.f, 0.f, 0.f, 0.f};
    float ksum = 0.f;
    __shared__ float ks[64][32];
    __shared__ float vs[64][32];
    const bf16_t* kbase = qkv + (size_t)b * NSEQ * 768 + 256 + hh * 32;
    const bf16_t* vbase = kbase + 256;
    int lr = threadIdx.x >> 2, lc = (threadIdx.x & 3) * 8;
    for (int c0 = n0; c0 < n1; c0 += 64) {
        int rows = min(64, n1 - c0);
        if (lr < rows) {
            bf16x8 kv8 = *(const bf16x8*)(kbase + (size_t)(c0 + lr) * 768 + lc);
            bf16x8 vv8 = *(const bf16x8*)(vbase + (size_t)(c0 + lr) * 768 + lc);
            #pragma unroll
            for (int j = 0; j < 8; ++j) {
                ks[lr][lc + j] = (float)kv8[j];
                vs[lr][lc + j] = (float)vv8[j];
            }
        }
        __syncthreads();
        for (int r = 0; r < rows; ++r) {
            float ek = __expf(ks[r][d]);
            if (eg == 0) ksum += ek;
            const float* vr = &vs[r][eg * 4];
            acc[0] += ek * vr[0]; acc[1] += ek * vr[1];
            acc[2] += ek * vr[2]; acc[3] += ek * vr[3];
        }
        __syncthreads();
    }
    float* cp = ctx_part + ((size_t)blk * 32 + d) * 32 + eg * 4;
    cp[0] = acc[0]; cp[1] = acc[1]; cp[2] = acc[2]; cp[3] = acc[3];
    if (eg == 0) colsum_part[blk * 32 + d] = ksum;
}

// ---------------- o = softmax(q)*scale @ ctx  -> bf16 att [M][256] ----------------
__global__ void o_kernel(const bf16_t* __restrict__ qkv, const float* __restrict__ ctx_part,
                         const float* __restrict__ colsum_part, bf16_t* __restrict__ att) {
    int bh = blockIdx.x, b = bh >> 3, hh = bh & 7;
    int chunk = blockIdx.y;
    __shared__ float ctx[1024];
    __shared__ float csum[32];
    int t = threadIdx.x;
    if (t < 32) {
        float s = 0.f;
        #pragma unroll
        for (int ss = 0; ss < 8; ++ss) s += colsum_part[(bh * 8 + ss) * 32 + t];
        csum[t] = s;
    }
    __syncthreads();
    for (int i = t; i < 1024; i += 256) {
        float s = 0.f;
        #pragma unroll
        for (int ss = 0; ss < 8; ++ss) s += ctx_part[(size_t)(bh * 8 + ss) * 1024 + i];
        ctx[i] = s / csum[i >> 5];
    }
    __syncthreads();
    int e = t & 31, grp = t >> 5;
    int n0 = chunk * 228, n1 = min(n0 + 228, NSEQ);
    for (int n = n0 + grp; n < n1; n += 8) {
        const bf16_t* q = qkv + (size_t)(b * NSEQ + n) * 768 + hh * 32;
        float qv = (float)q[e];
        float mx = qv;
        #pragma unroll
        for (int o2 = 16; o2 > 0; o2 >>= 1) mx = fmaxf(mx, __shfl_xor(mx, o2, 32));
        float ev = __expf(qv - mx);
        float sm = ev;
        #pragma unroll
        for (int o2 = 16; o2 > 0; o2 >>= 1) sm += __shfl_xor(sm, o2, 32);
        float p = ev * 0.17677669529663689f / sm;   // dh^-0.5 / sum
        float s = 0.f;
        #pragma unroll
        for (int dd = 0; dd < 32; ++dd) s += __shfl(p, dd, 32) * ctx[dd * 32 + e];
        att[(size_t)(b * NSEQ + n) * 256 + hh * 32 + e] = (bf16_t)s;
    }
}

// ---------------- classifier head: one wave per (b, cls) ----------------
__global__ void head_kernel(const float* __restrict__ h, const float* __restrict__ Wh,
                            const float* __restrict__ bh, float* __restrict__ out) {
    int idx = blockIdx.x;                 // 0..79 = b*5 + c
    int b = idx / 5, c = idx % 5;
    int lane = threadIdx.x;
    const float* xp = h + (size_t)b * NSEQ * 256;
    float s = 0.f;
    #pragma unroll
    for (int d0 = 0; d0 < 256; d0 += 64) s += xp[d0 + lane] * Wh[(d0 + lane) * 5 + c];
    s = wave_sum(s);
    if (lane == 0) out[idx] = s + bh[c];
}

extern "C" void kernel_launch(void* const* d_in, const int* in_sizes, int n_in,
                              void* d_out, int out_size, void* d_ws, size_t ws_size,
                              hipStream_t stream) {
    const int*   x    = (const int*)d_in[0];
    const float* emb  = (const float*)d_in[1];
    const float* ch   = (const float*)d_in[2];
    const float* cls  = (const float*)d_in[3];
    const float* Wq   = (const float*)d_in[4];
    const float* Wk   = (const float*)d_in[5];
    const float* Wv   = (const float*)d_in[6];
    const float* Wo   = (const float*)d_in[7];
    const float* bo   = (const float*)d_in[8];
    const float* g1   = (const float*)d_in[9];
    const float* b1   = (const float*)d_in[10];
    const float* W1   = (const float*)d_in[11];
    const float* bf1  = (const float*)d_in[12];
    const float* W2   = (const float*)d_in[13];
    const float* bf2  = (const float*)d_in[14];
    const float* g2   = (const float*)d_in[15];
    const float* b2   = (const float*)d_in[16];
    const float* Wh   = (const float*)d_in[17];
    const float* bh   = (const float*)d_in[18];

    char* ws = (char*)d_ws;
    size_t off = 0;
    float*  h      = (float*)(ws + off);  off += (size_t)M_ * 256 * 4;            // 33,570,816
    bf16_t* att    = (bf16_t*)(ws + off); off += (size_t)MPAD * 256 * 2;          // 16,842,752
    bf16_t* qkv    = (bf16_t*)(ws + off);
    bf16_t* f1     = (bf16_t*)(ws + off); off += (size_t)MPAD * 1024 * 2;         // 67,371,008 (f1 aliases qkv)
    float*  ctxp   = (float*)(ws + off);  off += (size_t)16 * 8 * 8 * 1024 * 4;   // 4,194,304
    float*  csump  = (float*)(ws + off);  off += (size_t)16 * 8 * 8 * 32 * 4;     // 131,072
    bf16_t* wqkv_p = (bf16_t*)(ws + off); off += (size_t)L_ * 768 * 256 * 2;      // 4,718,592
    bf16_t* wo_p   = (bf16_t*)(ws + off); off += (size_t)L_ * 256 * 256 * 2;      // 1,572,864
    bf16_t* w1_p   = (bf16_t*)(ws + off); off += (size_t)L_ * 1024 * 256 * 2;     // 6,291,456
    bf16_t* w2_p   = (bf16_t*)(ws + off); off += (size_t)L_ * 256 * 1024 * 2;     // 6,291,456
    (void)ws_size; (void)in_sizes; (void)n_in; (void)out_size;

    conv_wq3<<<9216, 256, 0, stream>>>(Wq, Wk, Wv, wqkv_p);
    conv_w<<<3072, 256, 0, stream>>>(Wo, wo_p, 256, 256);
    conv_w<<<12288, 256, 0, stream>>>(W1, w1_p, 256, 1024);
    conv_w<<<12288, 256, 0, stream>>>(W2, w2_p, 1024, 256);

    embed_kernel<<<M_ / 4, 256, 0, stream>>>(x, emb, ch, cls, h);

    for (int l = 0; l < L_; ++l) {
        // LN1 + QKV -> qkv bf16 [M][768]
        gemm_ar<0, 0, 3><<<dim3(2, 257), 512, 0, stream>>>(
            h, g1 + l * 256, b1 + l * 256, wqkv_p + (size_t)l * 768 * 256,
            nullptr, nullptr, qkv, 768);
        ctx_kernel<<<1024, 256, 0, stream>>>(qkv, ctxp, csump);
        o_kernel<<<dim3(128, 9), 256, 0, stream>>>(qkv, ctxp, csump, att);
        // Wo + bias + residual
        gemm_ar<1, 1, 1><<<dim3(2, 257), 512, 0, stream>>>(
            att, nullptr, nullptr, wo_p + (size_t)l * 256 * 256,
            bo + l * 256, h, nullptr, 256);
        // LN2 + FF1 + GELU -> f1 bf16 [M][1024]
        gemm_ar<0, 2, 4><<<dim3(2, 257), 512, 0, stream>>>(
            h, g2 + l * 256, b2 + l * 256, w1_p + (size_t)l * 1024 * 256,
            bf1 + l * 1024, nullptr, f1, 1024);
        // FF2 + bias + residual
        gemm_ff2c<<<dim3(2, 257), 512, 0, stream>>>(
            f1, w2_p + (size_t)l * 256 * 1024, bf2 + l * 256, h);
    }

    head_kernel<<<80, 64, 0, stream>>>(h, Wh, bh, (float*)d_out);
}